// Round 13
// baseline (125.896 us; speedup 1.0000x reference)
//
#include <hip/hip_runtime.h>

// VQ via MFMA (bf16 hi/lo compensated) + exact-recheck for near-ties.
// x [64,64,32,32] fp32, E [64,1024] fp32. rows n = b*1024+hw, N=65536.
// d_out: [0,4194304) quantized; [4194304] dict_loss; [4194305] commit_loss;
//   [4194306,+65536) indices as float.
// Pipeline: convert_e | convert_x -> mfma (top2 + flag) -> cleanup (exact
// fp32 for flagged rows) -> epilogue (gather, quantized, loss partials) -> loss.
// xh/xl bf16 [n][d] live temporarily in the out_q region (16 MB, exact fit);
// eh/el bf16 [k][d] + esq + partial in ws (~270 KB).

#define DDIM 64
#define KNUM 1024
#define HWN  1024
#define EPS  0.02f

typedef __attribute__((ext_vector_type(8))) short short8v;
typedef __attribute__((ext_vector_type(8))) unsigned short ushort8v;
typedef __attribute__((ext_vector_type(4))) float f32x4;

__device__ __forceinline__ unsigned short bf16_rn(float v) {
    unsigned u = __float_as_uint(v);
    return (unsigned short)((u + 0x7FFFu + ((u >> 16) & 1u)) >> 16);
}
__device__ __forceinline__ float bf16f(unsigned short h) {
    return __uint_as_float(((unsigned)h) << 16);
}

// ---- E: esq + bf16 hi/lo split, transposed to [k][d] ----
__global__ __launch_bounds__(256) void vq_convert_e(const float* __restrict__ E,
                                                    float* __restrict__ esq,
                                                    unsigned short* __restrict__ eh,
                                                    unsigned short* __restrict__ el) {
    int k = blockIdx.x * 256 + threadIdx.x;   // grid 4
    float s = 0.f;
    #pragma unroll 8
    for (int d = 0; d < DDIM; ++d) {
        float v = E[d * KNUM + k];
        s = fmaf(v, v, s);
        unsigned short h = bf16_rn(v);
        float lo = v - bf16f(h);              // exact split
        eh[k * DDIM + d] = h;
        el[k * DDIM + d] = bf16_rn(lo);
    }
    esq[k] = s;
}

// ---- x: bf16 hi/lo split, transposed to [n][d] (written into out_q region) ----
__global__ __launch_bounds__(256) void vq_convert_x(const float* __restrict__ x,
                                                    unsigned short* __restrict__ xh,
                                                    unsigned short* __restrict__ xl) {
    __shared__ float xlds[DDIM * 64];
    const int t  = threadIdx.x;
    const int wv = t >> 6, ln = t & 63;
    const int n0 = blockIdx.x * 64;           // grid 1024
    const int b  = n0 >> 10, hw0 = n0 & 1023;
    const float* xbase = x + (size_t)b * (DDIM * HWN) + hw0;
    #pragma unroll
    for (int it = 0; it < 4; ++it) {
        int dbase = it * 16 + wv * 4;
        int dsub  = ln >> 4;
        int off   = (ln & 15) * 4;
        const float* g = xbase + (dbase + dsub) * HWN + off;
        __builtin_amdgcn_global_load_lds(
            (const __attribute__((address_space(1))) void*)g,
            (__attribute__((address_space(3))) void*)&xlds[dbase * 64 + ln * 4],
            16, 0, 0);
    }
    __syncthreads();
    const int r = t & 63, dgrp = t >> 6;      // 4 dgroups x 16 d
    const int n = n0 + r;
    ushort8v h0, h1, l0, l1;
    #pragma unroll
    for (int i = 0; i < 8; ++i) {
        float v = xlds[(dgrp * 16 + i) * 64 + r];
        unsigned short h = bf16_rn(v);
        h0[i] = h; l0[i] = bf16_rn(v - bf16f(h));
    }
    #pragma unroll
    for (int i = 0; i < 8; ++i) {
        float v = xlds[(dgrp * 16 + 8 + i) * 64 + r];
        unsigned short h = bf16_rn(v);
        h1[i] = h; l1[i] = bf16_rn(v - bf16f(h));
    }
    *reinterpret_cast<ushort8v*>(xh + (size_t)n * DDIM + dgrp * 16)     = h0;
    *reinterpret_cast<ushort8v*>(xh + (size_t)n * DDIM + dgrp * 16 + 8) = h1;
    *reinterpret_cast<ushort8v*>(xl + (size_t)n * DDIM + dgrp * 16)     = l0;
    *reinterpret_cast<ushort8v*>(xl + (size_t)n * DDIM + dgrp * 16 + 8) = l1;
}

// ---- MFMA distance + per-row top2 argmin; flag near-ties (negated index) ----
__global__ __launch_bounds__(256, 2) void vq_mfma_kernel(const unsigned short* __restrict__ xh,
                                                         const unsigned short* __restrict__ xl,
                                                         const unsigned short* __restrict__ eh,
                                                         const unsigned short* __restrict__ el,
                                                         const float* __restrict__ esq,
                                                         float* __restrict__ oidx) {
    const int t = threadIdx.x;
    const int wv = t >> 6, l = t & 63;
    const int m = l & 15, g = l >> 4;
    const int tileBase = blockIdx.x * 8 + wv * 2;   // grid 512: 4096 tiles, 2/wave

    // A fragments: [tile][kstep], contiguous 8 bf16 along d
    short8v axh[2][2], axl[2][2];
    #pragma unroll
    for (int T = 0; T < 2; ++T) {
        int n0 = (tileBase + T) * 16;
        #pragma unroll
        for (int s = 0; s < 2; ++s) {
            axh[T][s] = *reinterpret_cast<const short8v*>(xh + (size_t)(n0 + m) * DDIM + s * 32 + g * 8);
            axl[T][s] = *reinterpret_cast<const short8v*>(xl + (size_t)(n0 + m) * DDIM + s * 32 + g * 8);
        }
    }

    float min1[2][4], min2[2][4]; int bk[2][4];
    #pragma unroll
    for (int T = 0; T < 2; ++T)
        #pragma unroll
        for (int j = 0; j < 4; ++j) { min1[T][j] = 3.4e38f; min2[T][j] = 3.4e38f; bk[T][j] = 0; }

    for (int kt = 0; kt < 64; ++kt) {
        const int k0 = kt * 16;
        const short8v bh0 = *reinterpret_cast<const short8v*>(eh + (size_t)(k0 + m) * DDIM + g * 8);
        const short8v bh1 = *reinterpret_cast<const short8v*>(eh + (size_t)(k0 + m) * DDIM + 32 + g * 8);
        const short8v bl0 = *reinterpret_cast<const short8v*>(el + (size_t)(k0 + m) * DDIM + g * 8);
        const short8v bl1 = *reinterpret_cast<const short8v*>(el + (size_t)(k0 + m) * DDIM + 32 + g * 8);
        const float esqv = esq[k0 + m];
        #pragma unroll
        for (int T = 0; T < 2; ++T) {
            f32x4 acc = {0.f, 0.f, 0.f, 0.f};
            acc = __builtin_amdgcn_mfma_f32_16x16x32_bf16(axh[T][0], bh0, acc, 0, 0, 0);
            acc = __builtin_amdgcn_mfma_f32_16x16x32_bf16(axh[T][1], bh1, acc, 0, 0, 0);
            acc = __builtin_amdgcn_mfma_f32_16x16x32_bf16(axh[T][0], bl0, acc, 0, 0, 0);
            acc = __builtin_amdgcn_mfma_f32_16x16x32_bf16(axh[T][1], bl1, acc, 0, 0, 0);
            acc = __builtin_amdgcn_mfma_f32_16x16x32_bf16(axl[T][0], bh0, acc, 0, 0, 0);
            acc = __builtin_amdgcn_mfma_f32_16x16x32_bf16(axl[T][1], bh1, acc, 0, 0, 0);
            #pragma unroll
            for (int j = 0; j < 4; ++j) {
                float dist = fmaf(-2.f, acc[j], esqv);
                bool lt = dist < min1[T][j];
                min2[T][j] = lt ? min1[T][j] : fminf(min2[T][j], dist);
                bk[T][j]   = lt ? (k0 + m)  : bk[T][j];
                min1[T][j] = lt ? dist      : min1[T][j];
            }
        }
    }

    // top-2 merge across the 16 k-class lanes of each row group
    #pragma unroll
    for (int T = 0; T < 2; ++T)
        #pragma unroll
        for (int j = 0; j < 4; ++j) {
            float m1 = min1[T][j], m2 = min2[T][j]; int k1 = bk[T][j];
            #pragma unroll
            for (int off = 8; off >= 1; off >>= 1) {
                float om1 = __shfl_xor(m1, off, 16);
                float om2 = __shfl_xor(m2, off, 16);
                int   ok1 = __shfl_xor(k1, off, 16);
                if (om1 < m1 || (om1 == m1 && ok1 < k1)) {
                    m2 = fminf(m1, om2); m1 = om1; k1 = ok1;
                } else {
                    m2 = fminf(m2, fminf(om1, om2) == om1 ? om2 : om1);
                    m2 = fminf(m2, om1 == m1 ? om2 : om1);  // conservative
                }
            }
            if (m == j) {
                int n = (tileBase + T) * 16 + g * 4 + j;
                bool flag = (m2 - m1) < EPS;
                oidx[n] = flag ? -(float)(k1 + 1) : (float)k1;
            }
        }
}

// ---- exact fp32 recheck for flagged rows ----
__global__ __launch_bounds__(256) void vq_cleanup(const float* __restrict__ x,
                                                  const float* __restrict__ E,
                                                  const float* __restrict__ esq,
                                                  float* __restrict__ oidx) {
    const int t = threadIdx.x;
    const int wave = blockIdx.x * 4 + (t >> 6);   // grid 1024 -> 4096 waves x 16 rows
    const int l = t & 63;
    const int rbase = wave * 16;
    float v = (l < 16) ? oidx[rbase + l] : 0.f;
    unsigned long long mask = __ballot(v < 0.f);
    while (mask) {
        int i = __ffsll(mask) - 1; mask &= mask - 1;
        int n = rbase + i;
        int b = n >> 10, hw = n & 1023;
        const float* xp = x + (size_t)b * (DDIM * HWN) + hw;
        float acc[16];
        #pragma unroll
        for (int kk = 0; kk < 16; ++kk) acc[kk] = 0.f;
        for (int d = 0; d < DDIM; ++d) {
            float xd = xp[d * HWN];                    // broadcast
            #pragma unroll
            for (int kk = 0; kk < 16; ++kk)
                acc[kk] = fmaf(xd, E[d * KNUM + kk * 64 + l], acc[kk]);
        }
        float bm = 3.4e38f; int bkk = KNUM;
        #pragma unroll
        for (int kk = 0; kk < 16; ++kk) {
            int k = kk * 64 + l;
            float dist = fmaf(-2.f, acc[kk], esq[k]);
            if (dist < bm) { bm = dist; bkk = k; }     // kk ascending -> first-min in lane
        }
        #pragma unroll
        for (int off = 32; off >= 1; off >>= 1) {
            float ob = __shfl_xor(bm, off);
            int   ok = __shfl_xor(bkk, off);
            if (ob < bm || (ob == bm && ok < bkk)) { bm = ob; bkk = ok; }
        }
        if (l == 0) oidx[n] = (float)bkk;
    }
}

// ---- gather quantized, write coalesced, loss partials ----
__global__ __launch_bounds__(256) void vq_epilogue(const float* __restrict__ x,
                                                   const float* __restrict__ E,
                                                   const float* __restrict__ oidx,
                                                   float* __restrict__ out_q,
                                                   float* __restrict__ partial) {
    __shared__ float xlds[DDIM * 64];
    __shared__ int   klds[64];
    __shared__ float redlds[4];
    const int t  = threadIdx.x;
    const int wv = t >> 6, ln = t & 63;
    const int n0 = blockIdx.x * 64;               // grid 1024
    const int b  = n0 >> 10, hw0 = n0 & 1023;
    const float* xbase = x + (size_t)b * (DDIM * HWN) + hw0;
    #pragma unroll
    for (int it = 0; it < 4; ++it) {
        int dbase = it * 16 + wv * 4;
        int dsub  = ln >> 4;
        int off   = (ln & 15) * 4;
        const float* g = xbase + (dbase + dsub) * HWN + off;
        __builtin_amdgcn_global_load_lds(
            (const __attribute__((address_space(1))) void*)g,
            (__attribute__((address_space(3))) void*)&xlds[dbase * 64 + ln * 4],
            16, 0, 0);
    }
    if (t < 64) { /* nothing yet */ }
    __syncthreads();
    if (t < 64) klds[t] = (int)oidx[n0 + t];
    __syncthreads();

    float lsum = 0.f;
    float* outbase = out_q + (size_t)b * (DDIM * HWN) + hw0;
    #pragma unroll 4
    for (int it = 0; it < 16; ++it) {
        int d = it * 4 + (t >> 6);
        int r = t & 63;
        int k = klds[r];
        float q  = E[d * KNUM + k];
        float xv = xlds[d * 64 + r];
        float diff = xv - q;
        lsum = fmaf(diff, diff, lsum);
        outbase[d * HWN + r] = q;
    }
    #pragma unroll
    for (int off = 32; off >= 1; off >>= 1)
        lsum += __shfl_xor(lsum, off);
    if ((t & 63) == 0) redlds[t >> 6] = lsum;
    __syncthreads();
    if (t == 0)
        partial[blockIdx.x] = (redlds[0] + redlds[1]) + (redlds[2] + redlds[3]);
}

__global__ __launch_bounds__(256) void vq_loss_kernel(const float* __restrict__ partial,
                                                      float* __restrict__ out_loss) {
    __shared__ float red[4];
    int t = threadIdx.x;
    float s = 0.f;
    #pragma unroll
    for (int it = 0; it < 4; ++it) s += partial[it * 256 + t];
    #pragma unroll
    for (int off = 32; off >= 1; off >>= 1) s += __shfl_xor(s, off);
    if ((t & 63) == 0) red[t >> 6] = s;
    __syncthreads();
    if (t == 0) {
        float loss = ((red[0] + red[1]) + (red[2] + red[3])) / 4194304.f;
        out_loss[0] = loss;
        out_loss[1] = loss;
    }
}

extern "C" void kernel_launch(void* const* d_in, const int* in_sizes, int n_in,
                              void* d_out, int out_size, void* d_ws, size_t ws_size,
                              hipStream_t stream) {
    const float* x = (const float*)d_in[0];
    const float* E = (const float*)d_in[1];
    float* out      = (float*)d_out;
    float* out_q    = out;
    float* out_loss = out + 4194304;
    float* oidx     = out + 4194306;

    float* esq     = (float*)d_ws;                  // 1024 f32
    float* partial = esq + 1024;                    // 1024 f32
    unsigned short* eh = (unsigned short*)(partial + 1024);  // 65536 us
    unsigned short* el = eh + KNUM * DDIM;                   // 65536 us
    // xh/xl temporarily occupy the out_q region (16 MB), overwritten by epilogue
    unsigned short* xh = (unsigned short*)out_q;
    unsigned short* xl = xh + (size_t)65536 * DDIM;

    vq_convert_e<<<4, 256, 0, stream>>>(E, esq, eh, el);
    vq_convert_x<<<1024, 256, 0, stream>>>(x, xh, xl);
    vq_mfma_kernel<<<512, 256, 0, stream>>>(xh, xl, eh, el, esq, oidx);
    vq_cleanup<<<1024, 256, 0, stream>>>(x, E, esq, oidx);
    vq_epilogue<<<1024, 256, 0, stream>>>(x, E, oidx, out_q, partial);
    vq_loss_kernel<<<1, 256, 0, stream>>>(partial, out_loss);
}

// Round 14
// 105.454 us; speedup vs baseline: 1.1938x; 1.1938x over previous
//
#include <hip/hip_runtime.h>

// VQ via MFMA (bf16 hi/lo compensated) + exact-recheck for near-ties. R14.
// x [64,64,32,32] fp32, E [64,1024] fp32. rows n = b*1024+hw, N=65536.
// d_out: [0,4194304) quantized; [4194304] dict_loss; [4194305] commit_loss;
//   [4194306,+65536) indices as float.
// Pipeline (4 launches): convert_e -> mfma_fused (in-kernel x split, T=2,
// 2-deep B prefetch, top2+flag) -> epilogue (exact recheck of flagged rows +
// gather + quantized + loss partials) -> loss.
// eh/el bf16 [k][d] + esq + partial in ws (~264 KB). No x staging buffers.

#define DDIM 64
#define KNUM 1024
#define HWN  1024
#define EPS  0.02f

typedef __attribute__((ext_vector_type(8))) short short8v;
typedef __attribute__((ext_vector_type(4))) float f32x4;

__device__ __forceinline__ unsigned short bf16_rn(float v) {
    unsigned u = __float_as_uint(v);
    return (unsigned short)((u + 0x7FFFu + ((u >> 16) & 1u)) >> 16);
}
__device__ __forceinline__ float bf16f(unsigned short h) {
    return __uint_as_float(((unsigned)h) << 16);
}

// ---- E: esq + bf16 hi/lo split, transposed to [k][d] ----
__global__ __launch_bounds__(256) void vq_convert_e(const float* __restrict__ E,
                                                    float* __restrict__ esq,
                                                    unsigned short* __restrict__ eh,
                                                    unsigned short* __restrict__ el) {
    int k = blockIdx.x * 256 + threadIdx.x;   // grid 4
    float s = 0.f;
    #pragma unroll 8
    for (int d = 0; d < DDIM; ++d) {
        float v = E[d * KNUM + k];
        s = fmaf(v, v, s);
        unsigned short h = bf16_rn(v);
        float lo = v - bf16f(h);              // exact split
        eh[k * DDIM + d] = h;
        el[k * DDIM + d] = bf16_rn(lo);
    }
    esq[k] = s;
}

// ---- MFMA distances + per-row top2 argmin; flag near-ties (negated index) ----
__global__ __launch_bounds__(256) void vq_mfma_kernel(const float* __restrict__ x,
                                                      const unsigned short* __restrict__ eh,
                                                      const unsigned short* __restrict__ el,
                                                      const float* __restrict__ esq,
                                                      float* __restrict__ oidx) {
    const int t = threadIdx.x;
    const int wv = t >> 6, l = t & 63;
    const int m = l & 15, g = l >> 4;
    const int tileBase = blockIdx.x * 8 + wv * 2;   // grid 512: 4096 tiles, 2/wave

    // ---- A fragments: load x fp32 directly (coalesced), split hi/lo in-reg ----
    short8v axh[2][2], axl[2][2];
    #pragma unroll
    for (int T = 0; T < 2; ++T) {
        const int n0 = (tileBase + T) * 16;
        const int bb = n0 >> 10, hw0 = n0 & 1023;
        const float* xg = x + (size_t)bb * (DDIM * HWN) + hw0 + m;
        #pragma unroll
        for (int s = 0; s < 2; ++s) {
            #pragma unroll
            for (int i = 0; i < 8; ++i) {
                float v = xg[(s * 32 + g * 8 + i) * HWN];
                unsigned short h = bf16_rn(v);
                axh[T][s][i] = (short)h;
                axl[T][s][i] = (short)bf16_rn(v - bf16f(h));
            }
        }
    }

    float min1[2][4], min2[2][4]; int bk[2][4];
    #pragma unroll
    for (int T = 0; T < 2; ++T)
        #pragma unroll
        for (int j = 0; j < 4; ++j) { min1[T][j] = 3.4e38f; min2[T][j] = 3.4e38f; bk[T][j] = 0; }

    // B-frag loader (k0 = kt*16)
    #define LOADB(b0, b1, b2, b3, eq, K0)                                                   \
        b0 = *reinterpret_cast<const short8v*>(eh + (size_t)((K0) + m) * DDIM + g * 8);     \
        b1 = *reinterpret_cast<const short8v*>(eh + (size_t)((K0) + m) * DDIM + 32 + g * 8);\
        b2 = *reinterpret_cast<const short8v*>(el + (size_t)((K0) + m) * DDIM + g * 8);     \
        b3 = *reinterpret_cast<const short8v*>(el + (size_t)((K0) + m) * DDIM + 32 + g * 8);\
        eq = esq[(K0) + m];

    #define STEP(b0, b1, b2, b3, eq, K0)                                                    \
        _Pragma("unroll")                                                                   \
        for (int T = 0; T < 2; ++T) {                                                       \
            f32x4 acc = {0.f, 0.f, 0.f, 0.f};                                               \
            acc = __builtin_amdgcn_mfma_f32_16x16x32_bf16(axh[T][0], b0, acc, 0, 0, 0);     \
            acc = __builtin_amdgcn_mfma_f32_16x16x32_bf16(axh[T][1], b1, acc, 0, 0, 0);     \
            acc = __builtin_amdgcn_mfma_f32_16x16x32_bf16(axh[T][0], b2, acc, 0, 0, 0);     \
            acc = __builtin_amdgcn_mfma_f32_16x16x32_bf16(axh[T][1], b3, acc, 0, 0, 0);     \
            acc = __builtin_amdgcn_mfma_f32_16x16x32_bf16(axl[T][0], b0, acc, 0, 0, 0);     \
            acc = __builtin_amdgcn_mfma_f32_16x16x32_bf16(axl[T][1], b1, acc, 0, 0, 0);     \
            _Pragma("unroll")                                                               \
            for (int j = 0; j < 4; ++j) {                                                   \
                float dist = fmaf(-2.f, acc[j], eq);                                        \
                bool lt = dist < min1[T][j];                                                \
                min2[T][j] = lt ? min1[T][j] : fminf(min2[T][j], dist);                     \
                bk[T][j]   = lt ? ((K0) + m) : bk[T][j];                                    \
                min1[T][j] = lt ? dist       : min1[T][j];                                  \
            }                                                                               \
        }

    short8v c0, c1, c2, c3; float ce;
    LOADB(c0, c1, c2, c3, ce, 0);
    for (int kt = 0; kt < 64; kt += 2) {
        short8v p0, p1, p2, p3; float pe;
        LOADB(p0, p1, p2, p3, pe, (kt + 1) * 16);     // prefetch odd
        STEP(c0, c1, c2, c3, ce, kt * 16);            // compute even
        const int k2 = (kt + 2 < 64) ? (kt + 2) * 16 : 0;
        LOADB(c0, c1, c2, c3, ce, k2);                // prefetch next even
        STEP(p0, p1, p2, p3, pe, (kt + 1) * 16);      // compute odd
    }
    #undef LOADB
    #undef STEP

    // top-2 merge across the 16 k-class lanes of each row group
    #pragma unroll
    for (int T = 0; T < 2; ++T)
        #pragma unroll
        for (int j = 0; j < 4; ++j) {
            float m1 = min1[T][j], m2 = min2[T][j]; int k1 = bk[T][j];
            #pragma unroll
            for (int off = 8; off >= 1; off >>= 1) {
                float om1 = __shfl_xor(m1, off, 16);
                float om2 = __shfl_xor(m2, off, 16);
                int   ok1 = __shfl_xor(k1, off, 16);
                if (om1 < m1 || (om1 == m1 && ok1 < k1)) {
                    m2 = fminf(m1, om2); m1 = om1; k1 = ok1;
                } else {
                    m2 = fminf(m2, fminf(om1, om2) == om1 ? om2 : om1);
                    m2 = fminf(m2, om1 == m1 ? om2 : om1);  // conservative
                }
            }
            if (m == j) {
                int n = (tileBase + T) * 16 + g * 4 + j;
                bool flag = (m2 - m1) < EPS;
                oidx[n] = flag ? -(float)(k1 + 1) : (float)k1;
            }
        }
}

// ---- exact recheck of flagged rows + gather + quantized + loss partials ----
__global__ __launch_bounds__(256) void vq_epilogue(const float* __restrict__ x,
                                                   const float* __restrict__ E,
                                                   const float* __restrict__ esq,
                                                   float* __restrict__ oidx,
                                                   float* __restrict__ out_q,
                                                   float* __restrict__ partial) {
    __shared__ float xlds[DDIM * 64];
    __shared__ int   klds[64];
    __shared__ float redlds[4];
    const int t  = threadIdx.x;
    const int wv = t >> 6, ln = t & 63;
    const int n0 = blockIdx.x * 64;               // grid 1024
    const int b  = n0 >> 10, hw0 = n0 & 1023;
    const float* xbase = x + (size_t)b * (DDIM * HWN) + hw0;
    #pragma unroll
    for (int it = 0; it < 4; ++it) {
        int dbase = it * 16 + wv * 4;
        int dsub  = ln >> 4;
        int off   = (ln & 15) * 4;
        const float* g = xbase + (dbase + dsub) * HWN + off;
        __builtin_amdgcn_global_load_lds(
            (const __attribute__((address_space(1))) void*)g,
            (__attribute__((address_space(3))) void*)&xlds[dbase * 64 + ln * 4],
            16, 0, 0);
    }
    __syncthreads();
    if (t < 64) klds[t] = (int)oidx[n0 + t];      // negative = flagged
    __syncthreads();

    // cleanup: wave wv handles flagged rows r = wv, wv+4, ... (uniform branch)
    for (int r = wv; r < 64; r += 4) {
        if (klds[r] >= 0) continue;
        float acc[16];
        #pragma unroll
        for (int kk = 0; kk < 16; ++kk) acc[kk] = 0.f;
        for (int d = 0; d < DDIM; ++d) {
            float xd = xlds[d * 64 + r];                   // broadcast
            #pragma unroll
            for (int kk = 0; kk < 16; ++kk)
                acc[kk] = fmaf(xd, E[d * KNUM + kk * 64 + ln], acc[kk]);
        }
        float bm = 3.4e38f; int bkk = KNUM;
        #pragma unroll
        for (int kk = 0; kk < 16; ++kk) {
            int k = kk * 64 + ln;
            float dist = fmaf(-2.f, acc[kk], esq[k]);
            if (dist < bm) { bm = dist; bkk = k; }         // kk ascending -> first-min
        }
        #pragma unroll
        for (int off = 32; off >= 1; off >>= 1) {
            float ob = __shfl_xor(bm, off);
            int   ok = __shfl_xor(bkk, off);
            if (ob < bm || (ob == bm && ok < bkk)) { bm = ob; bkk = ok; }
        }
        if (ln == 0) { klds[r] = bkk; oidx[n0 + r] = (float)bkk; }
    }
    __syncthreads();

    float lsum = 0.f;
    float* outbase = out_q + (size_t)b * (DDIM * HWN) + hw0;
    #pragma unroll 4
    for (int it = 0; it < 16; ++it) {
        int d = it * 4 + (t >> 6);
        int r = t & 63;
        int k = klds[r];
        float q  = E[d * KNUM + k];
        float xv = xlds[d * 64 + r];
        float diff = xv - q;
        lsum = fmaf(diff, diff, lsum);
        outbase[d * HWN + r] = q;
    }
    #pragma unroll
    for (int off = 32; off >= 1; off >>= 1)
        lsum += __shfl_xor(lsum, off);
    if ((t & 63) == 0) redlds[t >> 6] = lsum;
    __syncthreads();
    if (t == 0)
        partial[blockIdx.x] = (redlds[0] + redlds[1]) + (redlds[2] + redlds[3]);
}

__global__ __launch_bounds__(256) void vq_loss_kernel(const float* __restrict__ partial,
                                                      float* __restrict__ out_loss) {
    __shared__ float red[4];
    int t = threadIdx.x;
    float s = 0.f;
    #pragma unroll
    for (int it = 0; it < 4; ++it) s += partial[it * 256 + t];
    #pragma unroll
    for (int off = 32; off >= 1; off >>= 1) s += __shfl_xor(s, off);
    if ((t & 63) == 0) red[t >> 6] = s;
    __syncthreads();
    if (t == 0) {
        float loss = ((red[0] + red[1]) + (red[2] + red[3])) / 4194304.f;
        out_loss[0] = loss;
        out_loss[1] = loss;
    }
}

extern "C" void kernel_launch(void* const* d_in, const int* in_sizes, int n_in,
                              void* d_out, int out_size, void* d_ws, size_t ws_size,
                              hipStream_t stream) {
    const float* x = (const float*)d_in[0];
    const float* E = (const float*)d_in[1];
    float* out      = (float*)d_out;
    float* out_q    = out;
    float* out_loss = out + 4194304;
    float* oidx     = out + 4194306;

    float* esq     = (float*)d_ws;                           // 1024 f32
    float* partial = esq + 1024;                             // 1024 f32
    unsigned short* eh = (unsigned short*)(partial + 1024);  // 65536 us
    unsigned short* el = eh + KNUM * DDIM;                   // 65536 us

    vq_convert_e<<<4, 256, 0, stream>>>(E, esq, eh, el);
    vq_mfma_kernel<<<512, 256, 0, stream>>>(x, eh, el, esq, oidx);
    vq_epilogue<<<1024, 256, 0, stream>>>(x, E, esq, oidx, out_q, partial);
    vq_loss_kernel<<<1, 256, 0, stream>>>(partial, out_loss);
}

// Round 15
// 83.557 us; speedup vs baseline: 1.5067x; 1.2621x over previous
//
#include <hip/hip_runtime.h>

// VQ via MFMA (bf16 hi/lo compensated) + exact-recheck for near-ties. R15.
// x [64,64,32,32] fp32, E [64,1024] fp32. rows n = b*1024+hw, N=65536.
// d_out: [0,4194304) quantized; [4194304] dict_loss; [4194305] commit_loss;
//   [4194306,+65536) indices as float.
// R15 change: B operands (eh/el tiles) staged per-block into double-buffered
// LDS via global_load_lds (no dest register -> allocator can't demote it;
// R13/R14's register prefetch was silently sunk). XOR-swizzled layout
// (rule #21: linear LDS dest + inverse-swizzled per-lane global source +
// swizzled ds_read) -> b128 frag reads perfectly 8-balanced. esq staged to
// LDS once. A-frags stay as R14's in-register hi/lo split chain.

#define DDIM 64
#define KNUM 1024
#define HWN  1024
#define EPS  0.02f

typedef __attribute__((ext_vector_type(8))) short short8v;
typedef __attribute__((ext_vector_type(4))) float f32x4;

__device__ __forceinline__ unsigned short bf16_rn(float v) {
    unsigned u = __float_as_uint(v);
    return (unsigned short)((u + 0x7FFFu + ((u >> 16) & 1u)) >> 16);
}
__device__ __forceinline__ float bf16f(unsigned short h) {
    return __uint_as_float(((unsigned)h) << 16);
}

// ---- E: esq + bf16 hi/lo split, transposed to [k][d] ----
__global__ __launch_bounds__(256) void vq_convert_e(const float* __restrict__ E,
                                                    float* __restrict__ esq,
                                                    unsigned short* __restrict__ eh,
                                                    unsigned short* __restrict__ el) {
    int k = blockIdx.x * 256 + threadIdx.x;   // grid 4
    float s = 0.f;
    #pragma unroll 8
    for (int d = 0; d < DDIM; ++d) {
        float v = E[d * KNUM + k];
        s = fmaf(v, v, s);
        unsigned short h = bf16_rn(v);
        float lo = v - bf16f(h);              // exact split
        eh[k * DDIM + d] = h;
        el[k * DDIM + d] = bf16_rn(lo);
    }
    esq[k] = s;
}

// ---- MFMA distances + per-row top2 argmin; flag near-ties (negated index) ----
__global__ __launch_bounds__(256, 2) void vq_mfma_kernel(const float* __restrict__ x,
                                                         const unsigned short* __restrict__ eh,
                                                         const unsigned short* __restrict__ el,
                                                         const float* __restrict__ esq,
                                                         float* __restrict__ oidx) {
    // blds[buf]: 32 rows (0..15 = eh k-rows, 16..31 = el k-rows) x 128 B,
    // swizzled: byte_in_row ^= ((row&7)<<4). 4 KB per buffer.
    __shared__ unsigned short blds[2][2048];
    __shared__ float esqlds[KNUM];

    const int t = threadIdx.x;
    const int wv = t >> 6, l = t & 63;
    const int m = l & 15, g = l >> 4;
    const int tileBase = blockIdx.x * 8 + wv * 2;   // grid 512: 4096 tiles, 2/wave

    // ---- stage esq once (4 KB = 256 threads x 16 B) ----
    __builtin_amdgcn_global_load_lds(
        (const __attribute__((address_space(1))) void*)(esq + t * 4),
        (__attribute__((address_space(3))) void*)&esqlds[t * 4], 16, 0, 0);

    // ---- B staging geometry: thread stages 16 B; linear dest, swizzled src ----
    const int sr   = wv * 8 + (l >> 3);           // row 0..31 (wv<2: eh, wv>=2: el)
    const int sc   = (l & 7) * 16;                // linear byte col in row
    const int scsw = sc ^ ((sr & 7) << 4);        // inverse-swizzled source col
    const unsigned short* srcrow0 =
        (sr < 16) ? (eh + (size_t)sr * DDIM + (scsw >> 1))
                  : (el + (size_t)(sr - 16) * DDIM + (scsw >> 1));
    // per kt add k0*DDIM to source; LDS dest = blds[buf] + wv*512 + l*8 shorts.
    #define STAGE(BUF, K0)                                                              \
        __builtin_amdgcn_global_load_lds(                                               \
            (const __attribute__((address_space(1))) void*)(srcrow0 + (size_t)(K0) * DDIM), \
            (__attribute__((address_space(3))) void*)&blds[BUF][wv * 512 + l * 8],      \
            16, 0, 0);

    // ---- A fragments: load x fp32 (coalesced), split hi/lo in-reg ----
    short8v axh[2][2], axl[2][2];
    #pragma unroll
    for (int T = 0; T < 2; ++T) {
        const int n0 = (tileBase + T) * 16;
        const int bb = n0 >> 10, hw0 = n0 & 1023;
        const float* xg = x + (size_t)bb * (DDIM * HWN) + hw0 + m;
        #pragma unroll
        for (int s = 0; s < 2; ++s) {
            #pragma unroll
            for (int i = 0; i < 8; ++i) {
                float v = xg[(s * 32 + g * 8 + i) * HWN];
                unsigned short h = bf16_rn(v);
                axh[T][s][i] = (short)h;
                axl[T][s][i] = (short)bf16_rn(v - bf16f(h));
            }
        }
    }

    // swizzled ds_read offsets (shorts): frag = row m (hi) / 16+m (lo), col g*16 / 64+g*16
    const int off_h0 = (m * 128 + (((g * 16)      ) ^ ((m & 7) << 4))) >> 1;
    const int off_h1 = (m * 128 + (((64 + g * 16) ) ^ ((m & 7) << 4))) >> 1;
    const int off_l0 = off_h0 + 1024;   // +16 rows = +2048 B = +1024 shorts
    const int off_l1 = off_h1 + 1024;

    float min1[2][4], min2[2][4]; int bk[2][4];
    #pragma unroll
    for (int T = 0; T < 2; ++T)
        #pragma unroll
        for (int j = 0; j < 4; ++j) { min1[T][j] = 3.4e38f; min2[T][j] = 3.4e38f; bk[T][j] = 0; }

    STAGE(0, 0);
    __syncthreads();    // esq + buf0 staged (vmcnt drained by barrier)

    for (int kt = 0; kt < 64; ++kt) {
        const int cur = kt & 1;
        if (kt < 63) STAGE(cur ^ 1, (kt + 1) * 16);    // issue next tile early

        const unsigned short* bb = &blds[cur][0];
        const short8v bh0 = *reinterpret_cast<const short8v*>(bb + off_h0);
        const short8v bh1 = *reinterpret_cast<const short8v*>(bb + off_h1);
        const short8v bl0 = *reinterpret_cast<const short8v*>(bb + off_l0);
        const short8v bl1 = *reinterpret_cast<const short8v*>(bb + off_l1);
        const float esqv = esqlds[kt * 16 + m];

        #pragma unroll
        for (int T = 0; T < 2; ++T) {
            f32x4 acc = {0.f, 0.f, 0.f, 0.f};
            acc = __builtin_amdgcn_mfma_f32_16x16x32_bf16(axh[T][0], bh0, acc, 0, 0, 0);
            acc = __builtin_amdgcn_mfma_f32_16x16x32_bf16(axh[T][1], bh1, acc, 0, 0, 0);
            acc = __builtin_amdgcn_mfma_f32_16x16x32_bf16(axh[T][0], bl0, acc, 0, 0, 0);
            acc = __builtin_amdgcn_mfma_f32_16x16x32_bf16(axh[T][1], bl1, acc, 0, 0, 0);
            acc = __builtin_amdgcn_mfma_f32_16x16x32_bf16(axl[T][0], bh0, acc, 0, 0, 0);
            acc = __builtin_amdgcn_mfma_f32_16x16x32_bf16(axl[T][1], bh1, acc, 0, 0, 0);
            #pragma unroll
            for (int j = 0; j < 4; ++j) {
                float dist = fmaf(-2.f, acc[j], esqv);
                bool lt = dist < min1[T][j];
                min2[T][j] = lt ? min1[T][j] : fminf(min2[T][j], dist);
                bk[T][j]   = lt ? (kt * 16 + m) : bk[T][j];
                min1[T][j] = lt ? dist          : min1[T][j];
            }
        }
        __syncthreads();   // next buf staged; all waves done with cur
    }
    #undef STAGE

    // top-2 merge across the 16 k-class lanes of each row group
    #pragma unroll
    for (int T = 0; T < 2; ++T)
        #pragma unroll
        for (int j = 0; j < 4; ++j) {
            float m1 = min1[T][j], m2 = min2[T][j]; int k1 = bk[T][j];
            #pragma unroll
            for (int off = 8; off >= 1; off >>= 1) {
                float om1 = __shfl_xor(m1, off, 16);
                float om2 = __shfl_xor(m2, off, 16);
                int   ok1 = __shfl_xor(k1, off, 16);
                if (om1 < m1 || (om1 == m1 && ok1 < k1)) {
                    m2 = fminf(m1, om2); m1 = om1; k1 = ok1;
                } else {
                    m2 = fminf(m2, fminf(om1, om2) == om1 ? om2 : om1);
                    m2 = fminf(m2, om1 == m1 ? om2 : om1);  // conservative
                }
            }
            if (m == j) {
                int n = (tileBase + T) * 16 + g * 4 + j;
                bool flag = (m2 - m1) < EPS;
                oidx[n] = flag ? -(float)(k1 + 1) : (float)k1;
            }
        }
}

// ---- exact recheck of flagged rows + gather + quantized + loss partials ----
__global__ __launch_bounds__(256) void vq_epilogue(const float* __restrict__ x,
                                                   const float* __restrict__ E,
                                                   const float* __restrict__ esq,
                                                   float* __restrict__ oidx,
                                                   float* __restrict__ out_q,
                                                   float* __restrict__ partial) {
    __shared__ float xlds[DDIM * 64];
    __shared__ int   klds[64];
    __shared__ float redlds[4];
    const int t  = threadIdx.x;
    const int wv = t >> 6, ln = t & 63;
    const int n0 = blockIdx.x * 64;               // grid 1024
    const int b  = n0 >> 10, hw0 = n0 & 1023;
    const float* xbase = x + (size_t)b * (DDIM * HWN) + hw0;
    #pragma unroll
    for (int it = 0; it < 4; ++it) {
        int dbase = it * 16 + wv * 4;
        int dsub  = ln >> 4;
        int off   = (ln & 15) * 4;
        const float* g = xbase + (dbase + dsub) * HWN + off;
        __builtin_amdgcn_global_load_lds(
            (const __attribute__((address_space(1))) void*)g,
            (__attribute__((address_space(3))) void*)&xlds[dbase * 64 + ln * 4],
            16, 0, 0);
    }
    __syncthreads();
    if (t < 64) klds[t] = (int)oidx[n0 + t];      // negative = flagged
    __syncthreads();

    // cleanup: wave wv handles flagged rows r = wv, wv+4, ... (uniform branch)
    for (int r = wv; r < 64; r += 4) {
        if (klds[r] >= 0) continue;
        float acc[16];
        #pragma unroll
        for (int kk = 0; kk < 16; ++kk) acc[kk] = 0.f;
        for (int d = 0; d < DDIM; ++d) {
            float xd = xlds[d * 64 + r];                   // broadcast
            #pragma unroll
            for (int kk = 0; kk < 16; ++kk)
                acc[kk] = fmaf(xd, E[d * KNUM + kk * 64 + ln], acc[kk]);
        }
        float bm = 3.4e38f; int bkk = KNUM;
        #pragma unroll
        for (int kk = 0; kk < 16; ++kk) {
            int k = kk * 64 + ln;
            float dist = fmaf(-2.f, acc[kk], esq[k]);
            if (dist < bm) { bm = dist; bkk = k; }         // kk ascending -> first-min
        }
        #pragma unroll
        for (int off = 32; off >= 1; off >>= 1) {
            float ob = __shfl_xor(bm, off);
            int   ok = __shfl_xor(bkk, off);
            if (ob < bm || (ob == bm && ok < bkk)) { bm = ob; bkk = ok; }
        }
        if (ln == 0) { klds[r] = bkk; oidx[n0 + r] = (float)bkk; }
    }
    __syncthreads();

    float lsum = 0.f;
    float* outbase = out_q + (size_t)b * (DDIM * HWN) + hw0;
    #pragma unroll 4
    for (int it = 0; it < 16; ++it) {
        int d = it * 4 + (t >> 6);
        int r = t & 63;
        int k = klds[r];
        float q  = E[d * KNUM + k];
        float xv = xlds[d * 64 + r];
        float diff = xv - q;
        lsum = fmaf(diff, diff, lsum);
        outbase[d * HWN + r] = q;
    }
    #pragma unroll
    for (int off = 32; off >= 1; off >>= 1)
        lsum += __shfl_xor(lsum, off);
    if ((t & 63) == 0) redlds[t >> 6] = lsum;
    __syncthreads();
    if (t == 0)
        partial[blockIdx.x] = (redlds[0] + redlds[1]) + (redlds[2] + redlds[3]);
}

__global__ __launch_bounds__(256) void vq_loss_kernel(const float* __restrict__ partial,
                                                      float* __restrict__ out_loss) {
    __shared__ float red[4];
    int t = threadIdx.x;
    float s = 0.f;
    #pragma unroll
    for (int it = 0; it < 4; ++it) s += partial[it * 256 + t];
    #pragma unroll
    for (int off = 32; off >= 1; off >>= 1) s += __shfl_xor(s, off);
    if ((t & 63) == 0) red[t >> 6] = s;
    __syncthreads();
    if (t == 0) {
        float loss = ((red[0] + red[1]) + (red[2] + red[3])) / 4194304.f;
        out_loss[0] = loss;
        out_loss[1] = loss;
    }
}

extern "C" void kernel_launch(void* const* d_in, const int* in_sizes, int n_in,
                              void* d_out, int out_size, void* d_ws, size_t ws_size,
                              hipStream_t stream) {
    const float* x = (const float*)d_in[0];
    const float* E = (const float*)d_in[1];
    float* out      = (float*)d_out;
    float* out_q    = out;
    float* out_loss = out + 4194304;
    float* oidx     = out + 4194306;

    float* esq     = (float*)d_ws;                           // 1024 f32
    float* partial = esq + 1024;                             // 1024 f32
    unsigned short* eh = (unsigned short*)(partial + 1024);  // 65536 us
    unsigned short* el = eh + KNUM * DDIM;                   // 65536 us

    vq_convert_e<<<4, 256, 0, stream>>>(E, esq, eh, el);
    vq_mfma_kernel<<<512, 256, 0, stream>>>(x, eh, el, esq, oidx);
    vq_epilogue<<<1024, 256, 0, stream>>>(x, E, esq, oidx, out_q, partial);
    vq_loss_kernel<<<1, 256, 0, stream>>>(partial, out_loss);
}

// Round 16
// 74.131 us; speedup vs baseline: 1.6983x; 1.1271x over previous
//
#include <hip/hip_runtime.h>

// VQ via MFMA (bf16 hi/lo compensated) + exact-recheck for near-ties. R16.
// x [64,64,32,32] fp32, E [64,1024] fp32. rows n = b*1024+hw, N=65536.
// d_out: [0,4194304) quantized; [4194304] dict_loss; [4194305] commit_loss;
//   [4194306,+65536) indices as float.
// R16 change vs R15: phase-chunked double buffering. 8 kt-tiles (32 KB)
// staged per phase; 2 x 32 KB LDS buffers (64 KB static, the full limit);
// barriers 64 -> 9 (the per-kt barrier+vmcnt(0) drain was the stall). Inside
// a phase: 8 barrier-free kt steps, MFMA acc split into 2 chains (4+2 deep).
// esq read per-lane from L2 (no LDS left). Swizzle identical to R15.

#define DDIM 64
#define KNUM 1024
#define HWN  1024
#define EPS  0.02f

typedef __attribute__((ext_vector_type(8))) short short8v;
typedef __attribute__((ext_vector_type(4))) float f32x4;

__device__ __forceinline__ unsigned short bf16_rn(float v) {
    unsigned u = __float_as_uint(v);
    return (unsigned short)((u + 0x7FFFu + ((u >> 16) & 1u)) >> 16);
}
__device__ __forceinline__ float bf16f(unsigned short h) {
    return __uint_as_float(((unsigned)h) << 16);
}

// ---- E: esq + bf16 hi/lo split, transposed to [k][d] ----
__global__ __launch_bounds__(256) void vq_convert_e(const float* __restrict__ E,
                                                    float* __restrict__ esq,
                                                    unsigned short* __restrict__ eh,
                                                    unsigned short* __restrict__ el) {
    int k = blockIdx.x * 256 + threadIdx.x;   // grid 4
    float s = 0.f;
    #pragma unroll 8
    for (int d = 0; d < DDIM; ++d) {
        float v = E[d * KNUM + k];
        s = fmaf(v, v, s);
        unsigned short h = bf16_rn(v);
        float lo = v - bf16f(h);              // exact split
        eh[k * DDIM + d] = h;
        el[k * DDIM + d] = bf16_rn(lo);
    }
    esq[k] = s;
}

// ---- MFMA distances + per-row top2 argmin; flag near-ties (negated index) ----
__global__ __launch_bounds__(256, 2) void vq_mfma_kernel(const float* __restrict__ x,
                                                         const unsigned short* __restrict__ eh,
                                                         const unsigned short* __restrict__ el,
                                                         const float* __restrict__ esq,
                                                         float* __restrict__ oidx) {
    // blds[buf]: 8 kt-tiles x (32 rows x 128 B swizzled) = 32 KB per buffer.
    // Row layout per tile: rows 0..15 = eh k-rows, 16..31 = el k-rows;
    // byte_in_row ^= ((row&7)<<4).
    __shared__ unsigned short blds[2][16384];

    const int t = threadIdx.x;
    const int wv = t >> 6, l = t & 63;
    const int m = l & 15, g = l >> 4;
    const int tileBase = blockIdx.x * 8 + wv * 2;   // grid 512: 4096 tiles, 2/wave

    // ---- staging geometry: thread stages 16 B per kt-tile; linear dest ----
    const int sr   = wv * 8 + (l >> 3);           // row 0..31 in tile
    const int sc   = (l & 7) * 16;                // linear byte col in row
    const int scsw = sc ^ ((sr & 7) << 4);        // inverse-swizzled source col
    const unsigned short* srcrow0 =
        (sr < 16) ? (eh + (size_t)sr * DDIM + (scsw >> 1))
                  : (el + (size_t)(sr - 16) * DDIM + (scsw >> 1));
    // stage phase P (8 kt-tiles) into BUF
    #define STAGEPH(BUF, P)                                                                  \
        _Pragma("unroll")                                                                    \
        for (int q = 0; q < 8; ++q)                                                          \
            __builtin_amdgcn_global_load_lds(                                                \
                (const __attribute__((address_space(1))) void*)(srcrow0 + (size_t)((P) * 8 + q) * 16 * DDIM), \
                (__attribute__((address_space(3))) void*)&blds[BUF][q * 2048 + wv * 512 + l * 8], \
                16, 0, 0);

    // ---- A fragments: load x fp32 (coalesced), split hi/lo in-reg ----
    short8v axh[2][2], axl[2][2];
    #pragma unroll
    for (int T = 0; T < 2; ++T) {
        const int n0 = (tileBase + T) * 16;
        const int bb = n0 >> 10, hw0 = n0 & 1023;
        const float* xg = x + (size_t)bb * (DDIM * HWN) + hw0 + m;
        #pragma unroll
        for (int s = 0; s < 2; ++s) {
            #pragma unroll
            for (int i = 0; i < 8; ++i) {
                float v = xg[(s * 32 + g * 8 + i) * HWN];
                unsigned short h = bf16_rn(v);
                axh[T][s][i] = (short)h;
                axl[T][s][i] = (short)bf16_rn(v - bf16f(h));
            }
        }
    }

    // swizzled ds_read offsets (shorts) within a kt-tile
    const int off_h0 = (m * 128 + (((g * 16)     ) ^ ((m & 7) << 4))) >> 1;
    const int off_h1 = (m * 128 + (((64 + g * 16)) ^ ((m & 7) << 4))) >> 1;
    const int off_l0 = off_h0 + 1024;   // +16 rows = +2048 B
    const int off_l1 = off_h1 + 1024;

    float min1[2][4], min2[2][4]; int bk[2][4];
    #pragma unroll
    for (int T = 0; T < 2; ++T)
        #pragma unroll
        for (int j = 0; j < 4; ++j) { min1[T][j] = 3.4e38f; min2[T][j] = 3.4e38f; bk[T][j] = 0; }

    STAGEPH(0, 0);
    __syncthreads();    // buf0 staged

    for (int p = 0; p < 8; ++p) {
        const int cur = p & 1;
        if (p < 7) STAGEPH(cur ^ 1, p + 1);       // issue next phase early

        #pragma unroll
        for (int ktl = 0; ktl < 8; ++ktl) {
            const int kt = p * 8 + ktl;
            const unsigned short* bb = &blds[cur][ktl * 2048];
            const short8v bh0 = *reinterpret_cast<const short8v*>(bb + off_h0);
            const short8v bh1 = *reinterpret_cast<const short8v*>(bb + off_h1);
            const short8v bl0 = *reinterpret_cast<const short8v*>(bb + off_l0);
            const short8v bl1 = *reinterpret_cast<const short8v*>(bb + off_l1);
            const float esqv = esq[kt * 16 + m];   // per-lane, L2-hot

            #pragma unroll
            for (int T = 0; T < 2; ++T) {
                f32x4 accA = {0.f, 0.f, 0.f, 0.f};
                f32x4 accB = {0.f, 0.f, 0.f, 0.f};
                accA = __builtin_amdgcn_mfma_f32_16x16x32_bf16(axh[T][0], bh0, accA, 0, 0, 0);
                accA = __builtin_amdgcn_mfma_f32_16x16x32_bf16(axh[T][1], bh1, accA, 0, 0, 0);
                accB = __builtin_amdgcn_mfma_f32_16x16x32_bf16(axh[T][0], bl0, accB, 0, 0, 0);
                accB = __builtin_amdgcn_mfma_f32_16x16x32_bf16(axh[T][1], bl1, accB, 0, 0, 0);
                accA = __builtin_amdgcn_mfma_f32_16x16x32_bf16(axl[T][0], bh0, accA, 0, 0, 0);
                accA = __builtin_amdgcn_mfma_f32_16x16x32_bf16(axl[T][1], bh1, accA, 0, 0, 0);
                #pragma unroll
                for (int j = 0; j < 4; ++j) {
                    float dist = fmaf(-2.f, accA[j] + accB[j], esqv);
                    bool lt = dist < min1[T][j];
                    min2[T][j] = lt ? min1[T][j] : fminf(min2[T][j], dist);
                    bk[T][j]   = lt ? (kt * 16 + m) : bk[T][j];
                    min1[T][j] = lt ? dist          : min1[T][j];
                }
            }
        }
        __syncthreads();   // all waves done with cur; next buf staged (drained)
    }
    #undef STAGEPH

    // top-2 merge across the 16 k-class lanes of each row group
    #pragma unroll
    for (int T = 0; T < 2; ++T)
        #pragma unroll
        for (int j = 0; j < 4; ++j) {
            float m1 = min1[T][j], m2 = min2[T][j]; int k1 = bk[T][j];
            #pragma unroll
            for (int off = 8; off >= 1; off >>= 1) {
                float om1 = __shfl_xor(m1, off, 16);
                float om2 = __shfl_xor(m2, off, 16);
                int   ok1 = __shfl_xor(k1, off, 16);
                if (om1 < m1 || (om1 == m1 && ok1 < k1)) {
                    m2 = fminf(m1, om2); m1 = om1; k1 = ok1;
                } else {
                    m2 = fminf(m2, fminf(om1, om2) == om1 ? om2 : om1);
                    m2 = fminf(m2, om1 == m1 ? om2 : om1);  // conservative
                }
            }
            if (m == j) {
                int n = (tileBase + T) * 16 + g * 4 + j;
                bool flag = (m2 - m1) < EPS;
                oidx[n] = flag ? -(float)(k1 + 1) : (float)k1;
            }
        }
}

// ---- exact recheck of flagged rows + gather + quantized + loss partials ----
__global__ __launch_bounds__(256) void vq_epilogue(const float* __restrict__ x,
                                                   const float* __restrict__ E,
                                                   const float* __restrict__ esq,
                                                   float* __restrict__ oidx,
                                                   float* __restrict__ out_q,
                                                   float* __restrict__ partial) {
    __shared__ float xlds[DDIM * 64];
    __shared__ int   klds[64];
    __shared__ float redlds[4];
    const int t  = threadIdx.x;
    const int wv = t >> 6, ln = t & 63;
    const int n0 = blockIdx.x * 64;               // grid 1024
    const int b  = n0 >> 10, hw0 = n0 & 1023;
    const float* xbase = x + (size_t)b * (DDIM * HWN) + hw0;
    #pragma unroll
    for (int it = 0; it < 4; ++it) {
        int dbase = it * 16 + wv * 4;
        int dsub  = ln >> 4;
        int off   = (ln & 15) * 4;
        const float* g = xbase + (dbase + dsub) * HWN + off;
        __builtin_amdgcn_global_load_lds(
            (const __attribute__((address_space(1))) void*)g,
            (__attribute__((address_space(3))) void*)&xlds[dbase * 64 + ln * 4],
            16, 0, 0);
    }
    __syncthreads();
    if (t < 64) klds[t] = (int)oidx[n0 + t];      // negative = flagged
    __syncthreads();

    // cleanup: wave wv handles flagged rows r = wv, wv+4, ... (uniform branch)
    for (int r = wv; r < 64; r += 4) {
        if (klds[r] >= 0) continue;
        float acc[16];
        #pragma unroll
        for (int kk = 0; kk < 16; ++kk) acc[kk] = 0.f;
        for (int d = 0; d < DDIM; ++d) {
            float xd = xlds[d * 64 + r];                   // broadcast
            #pragma unroll
            for (int kk = 0; kk < 16; ++kk)
                acc[kk] = fmaf(xd, E[d * KNUM + kk * 64 + ln], acc[kk]);
        }
        float bm = 3.4e38f; int bkk = KNUM;
        #pragma unroll
        for (int kk = 0; kk < 16; ++kk) {
            int k = kk * 64 + ln;
            float dist = fmaf(-2.f, acc[kk], esq[k]);
            if (dist < bm) { bm = dist; bkk = k; }         // kk ascending -> first-min
        }
        #pragma unroll
        for (int off = 32; off >= 1; off >>= 1) {
            float ob = __shfl_xor(bm, off);
            int   ok = __shfl_xor(bkk, off);
            if (ob < bm || (ob == bm && ok < bkk)) { bm = ob; bkk = ok; }
        }
        if (ln == 0) { klds[r] = bkk; oidx[n0 + r] = (float)bkk; }
    }
    __syncthreads();

    float lsum = 0.f;
    float* outbase = out_q + (size_t)b * (DDIM * HWN) + hw0;
    #pragma unroll 4
    for (int it = 0; it < 16; ++it) {
        int d = it * 4 + (t >> 6);
        int r = t & 63;
        int k = klds[r];
        float q  = E[d * KNUM + k];
        float xv = xlds[d * 64 + r];
        float diff = xv - q;
        lsum = fmaf(diff, diff, lsum);
        outbase[d * HWN + r] = q;
    }
    #pragma unroll
    for (int off = 32; off >= 1; off >>= 1)
        lsum += __shfl_xor(lsum, off);
    if ((t & 63) == 0) redlds[t >> 6] = lsum;
    __syncthreads();
    if (t == 0)
        partial[blockIdx.x] = (redlds[0] + redlds[1]) + (redlds[2] + redlds[3]);
}

__global__ __launch_bounds__(256) void vq_loss_kernel(const float* __restrict__ partial,
                                                      float* __restrict__ out_loss) {
    __shared__ float red[4];
    int t = threadIdx.x;
    float s = 0.f;
    #pragma unroll
    for (int it = 0; it < 4; ++it) s += partial[it * 256 + t];
    #pragma unroll
    for (int off = 32; off >= 1; off >>= 1) s += __shfl_xor(s, off);
    if ((t & 63) == 0) red[t >> 6] = s;
    __syncthreads();
    if (t == 0) {
        float loss = ((red[0] + red[1]) + (red[2] + red[3])) / 4194304.f;
        out_loss[0] = loss;
        out_loss[1] = loss;
    }
}

extern "C" void kernel_launch(void* const* d_in, const int* in_sizes, int n_in,
                              void* d_out, int out_size, void* d_ws, size_t ws_size,
                              hipStream_t stream) {
    const float* x = (const float*)d_in[0];
    const float* E = (const float*)d_in[1];
    float* out      = (float*)d_out;
    float* out_q    = out;
    float* out_loss = out + 4194304;
    float* oidx     = out + 4194306;

    float* esq     = (float*)d_ws;                           // 1024 f32
    float* partial = esq + 1024;                             // 1024 f32
    unsigned short* eh = (unsigned short*)(partial + 1024);  // 65536 us
    unsigned short* el = eh + KNUM * DDIM;                   // 65536 us

    vq_convert_e<<<4, 256, 0, stream>>>(E, esq, eh, el);
    vq_mfma_kernel<<<512, 256, 0, stream>>>(x, eh, el, esq, oidx);
    vq_epilogue<<<1024, 256, 0, stream>>>(x, E, esq, oidx, out_q, partial);
    vq_loss_kernel<<<1, 256, 0, stream>>>(partial, out_loss);
}

// Round 17
// 64.872 us; speedup vs baseline: 1.9407x; 1.1427x over previous
//
#include <hip/hip_runtime.h>

// VQ via MFMA (bf16 hi/lo compensated) + exact-recheck for near-ties. R17.
// x [64,64,32,32] fp32, E [64,1024] fp32. rows n = b*1024+hw, N=65536.
// d_out: [0,4194304) quantized; [4194304] dict_loss; [4194305] commit_loss;
//   [4194306,+65536) indices as float.
// R17 vs R16: (1) T=1, grid 1024, 4-kt phases, LDS 32KB, launch_bounds(256,4)
// -> 4 blocks/CU (2x TLP); (2) single zero-C MFMA chain + med3-style top-2
// (VALU trim); (3) cleanup+epilogue FUSED into the mfma kernel (block = 64
// rows = old epilogue geometry; xlds aliases dead blds) -> 2 fewer dispatches,
// no oidx round-trip, no 16MB x re-stage.

#define DDIM 64
#define KNUM 1024
#define HWN  1024
#define EPS  0.02f

typedef __attribute__((ext_vector_type(8))) short short8v;
typedef __attribute__((ext_vector_type(4))) float f32x4;

__device__ __forceinline__ unsigned short bf16_rn(float v) {
    unsigned u = __float_as_uint(v);
    return (unsigned short)((u + 0x7FFFu + ((u >> 16) & 1u)) >> 16);
}
__device__ __forceinline__ float bf16f(unsigned short h) {
    return __uint_as_float(((unsigned)h) << 16);
}

// ---- E: esq + bf16 hi/lo split, transposed to [k][d] ----
__global__ __launch_bounds__(256) void vq_convert_e(const float* __restrict__ E,
                                                    float* __restrict__ esq,
                                                    unsigned short* __restrict__ eh,
                                                    unsigned short* __restrict__ el) {
    int k = blockIdx.x * 256 + threadIdx.x;   // grid 4
    float s = 0.f;
    #pragma unroll 8
    for (int d = 0; d < DDIM; ++d) {
        float v = E[d * KNUM + k];
        s = fmaf(v, v, s);
        unsigned short h = bf16_rn(v);
        float lo = v - bf16f(h);              // exact split
        eh[k * DDIM + d] = h;
        el[k * DDIM + d] = bf16_rn(lo);
    }
    esq[k] = s;
}

// ---- fused: MFMA distances + top2 argmin + cleanup + quantized + loss ----
__global__ __launch_bounds__(256, 4) void vq_mfma_fused(const float* __restrict__ x,
                                                        const float* __restrict__ E,
                                                        const unsigned short* __restrict__ eh,
                                                        const unsigned short* __restrict__ el,
                                                        const float* __restrict__ esq,
                                                        float* __restrict__ oidx,
                                                        float* __restrict__ out_q,
                                                        float* __restrict__ partial) {
    // blds[buf]: 4 kt-tiles x (32 rows x 128 B swizzled) = 16 KB per buffer.
    // Rows 0..15 = eh k-rows, 16..31 = el k-rows; byte_in_row ^= ((row&7)<<4).
    __shared__ unsigned short blds[2][8192];
    __shared__ int   klds[64];
    __shared__ float redlds[4];

    const int t = threadIdx.x;
    const int wv = t >> 6, l = t & 63;
    const int m = l & 15, g = l >> 4;
    const int tile = blockIdx.x * 4 + wv;     // grid 1024: 4096 tiles, 1/wave
    const int n0 = blockIdx.x * 64;           // block rows
    const int b  = n0 >> 10, hw0 = n0 & 1023;

    // ---- staging geometry: 256 threads stage one 4KB kt-tile ----
    const int sr   = t >> 3;                  // row 0..31 in tile
    const int sc   = (t & 7) * 16;            // linear byte col
    const int scsw = sc ^ ((sr & 7) << 4);    // inverse-swizzled source col
    const unsigned short* srcrow0 =
        (sr < 16) ? (eh + (size_t)sr * DDIM + (scsw >> 1))
                  : (el + (size_t)(sr - 16) * DDIM + (scsw >> 1));
    #define STAGEPH(BUF, P)                                                                  \
        _Pragma("unroll")                                                                    \
        for (int q = 0; q < 4; ++q)                                                          \
            __builtin_amdgcn_global_load_lds(                                                \
                (const __attribute__((address_space(1))) void*)(srcrow0 + (size_t)((P) * 4 + q) * 16 * DDIM), \
                (__attribute__((address_space(3))) void*)&blds[BUF][q * 2048 + t * 8],       \
                16, 0, 0);

    // ---- A fragments: load x fp32 (coalesced), split hi/lo in-reg ----
    short8v axh[2], axl[2];
    {
        const int tn0 = tile * 16;
        const int tb = tn0 >> 10, thw = tn0 & 1023;
        const float* xg = x + (size_t)tb * (DDIM * HWN) + thw + m;
        #pragma unroll
        for (int s = 0; s < 2; ++s) {
            #pragma unroll
            for (int i = 0; i < 8; ++i) {
                float v = xg[(s * 32 + g * 8 + i) * HWN];
                unsigned short h = bf16_rn(v);
                axh[s][i] = (short)h;
                axl[s][i] = (short)bf16_rn(v - bf16f(h));
            }
        }
    }

    // swizzled ds_read offsets (shorts) within a kt-tile
    const int off_h0 = (m * 128 + (((g * 16)     ) ^ ((m & 7) << 4))) >> 1;
    const int off_h1 = (m * 128 + (((64 + g * 16)) ^ ((m & 7) << 4))) >> 1;
    const int off_l0 = off_h0 + 1024;
    const int off_l1 = off_h1 + 1024;

    float min1[4], min2[4]; int bk[4];
    #pragma unroll
    for (int j = 0; j < 4; ++j) { min1[j] = 3.4e38f; min2[j] = 3.4e38f; bk[j] = 0; }

    const f32x4 zf = {0.f, 0.f, 0.f, 0.f};

    STAGEPH(0, 0);
    __syncthreads();

    for (int p = 0; p < 16; ++p) {
        const int cur = p & 1;
        if (p < 15) STAGEPH(cur ^ 1, p + 1);

        #pragma unroll
        for (int ktl = 0; ktl < 4; ++ktl) {
            const int kt = p * 4 + ktl;
            const unsigned short* bb = &blds[cur][ktl * 2048];
            const short8v bh0 = *reinterpret_cast<const short8v*>(bb + off_h0);
            const short8v bh1 = *reinterpret_cast<const short8v*>(bb + off_h1);
            const short8v bl0 = *reinterpret_cast<const short8v*>(bb + off_l0);
            const short8v bl1 = *reinterpret_cast<const short8v*>(bb + off_l1);
            const float esqv = esq[kt * 16 + m];   // per-lane, L2-hot

            f32x4 acc;
            acc = __builtin_amdgcn_mfma_f32_16x16x32_bf16(axh[0], bh0, zf,  0, 0, 0);
            acc = __builtin_amdgcn_mfma_f32_16x16x32_bf16(axh[1], bh1, acc, 0, 0, 0);
            acc = __builtin_amdgcn_mfma_f32_16x16x32_bf16(axh[0], bl0, acc, 0, 0, 0);
            acc = __builtin_amdgcn_mfma_f32_16x16x32_bf16(axh[1], bl1, acc, 0, 0, 0);
            acc = __builtin_amdgcn_mfma_f32_16x16x32_bf16(axl[0], bh0, acc, 0, 0, 0);
            acc = __builtin_amdgcn_mfma_f32_16x16x32_bf16(axl[1], bh1, acc, 0, 0, 0);

            #pragma unroll
            for (int j = 0; j < 4; ++j) {
                float dist = fmaf(-2.f, acc[j], esqv);
                // med3-style top-2: min2' = min(max(dist,min1), min2)
                min2[j] = fminf(fmaxf(dist, min1[j]), min2[j]);
                bool lt = dist < min1[j];
                bk[j]   = lt ? (kt * 16 + m) : bk[j];
                min1[j] = fminf(min1[j], dist);
            }
        }
        __syncthreads();
    }
    #undef STAGEPH

    // ---- issue x fp32 staging into dead blds (overlaps with merge below) ----
    float* xlds = reinterpret_cast<float*>(&blds[0][0]);   // 16 KB [d][64 rows]
    {
        const float* xbase = x + (size_t)b * (DDIM * HWN) + hw0;
        #pragma unroll
        for (int it = 0; it < 4; ++it) {
            int dbase = it * 16 + wv * 4;
            int dsub  = l >> 4;
            int off   = (l & 15) * 4;
            const float* gp = xbase + (dbase + dsub) * HWN + off;
            __builtin_amdgcn_global_load_lds(
                (const __attribute__((address_space(1))) void*)gp,
                (__attribute__((address_space(3))) void*)&xlds[dbase * 64 + l * 4],
                16, 0, 0);
        }
    }

    // ---- top-2 merge across the 16 k-class lanes of each row group ----
    #pragma unroll
    for (int j = 0; j < 4; ++j) {
        float m1 = min1[j], m2 = min2[j]; int k1 = bk[j];
        #pragma unroll
        for (int off = 8; off >= 1; off >>= 1) {
            float om1 = __shfl_xor(m1, off, 16);
            float om2 = __shfl_xor(m2, off, 16);
            int   ok1 = __shfl_xor(k1, off, 16);
            if (om1 < m1 || (om1 == m1 && ok1 < k1)) {
                m2 = fminf(m1, om2); m1 = om1; k1 = ok1;
            } else {
                m2 = fminf(m2, fminf(om1, om2) == om1 ? om2 : om1);
                m2 = fminf(m2, om1 == m1 ? om2 : om1);  // conservative
            }
        }
        if (m == j) {
            int r = wv * 16 + g * 4 + j;
            klds[r] = (m2 - m1 < EPS) ? -(k1 + 1) : k1;   // negative = flagged
        }
    }
    __syncthreads();   // xlds staged (vmcnt drained) + klds visible

    // ---- cleanup: exact fp32 recheck for flagged rows (rare) ----
    for (int r = wv; r < 64; r += 4) {
        if (klds[r] >= 0) continue;
        float acc[16];
        #pragma unroll
        for (int kk = 0; kk < 16; ++kk) acc[kk] = 0.f;
        for (int d = 0; d < DDIM; ++d) {
            float xd = xlds[d * 64 + r];                   // broadcast
            #pragma unroll
            for (int kk = 0; kk < 16; ++kk)
                acc[kk] = fmaf(xd, E[d * KNUM + kk * 64 + l], acc[kk]);
        }
        float bm = 3.4e38f; int bkk = KNUM;
        #pragma unroll
        for (int kk = 0; kk < 16; ++kk) {
            int k = kk * 64 + l;
            float dist = fmaf(-2.f, acc[kk], esq[k]);
            if (dist < bm) { bm = dist; bkk = k; }         // kk ascending -> first-min
        }
        #pragma unroll
        for (int off = 32; off >= 1; off >>= 1) {
            float ob = __shfl_xor(bm, off);
            int   ok = __shfl_xor(bkk, off);
            if (ob < bm || (ob == bm && ok < bkk)) { bm = ob; bkk = ok; }
        }
        if (l == 0) klds[r] = bkk;
    }
    __syncthreads();

    // ---- gather quantized, write coalesced, loss partial, indices ----
    float lsum = 0.f;
    float* outbase = out_q + (size_t)b * (DDIM * HWN) + hw0;
    #pragma unroll 4
    for (int it = 0; it < 16; ++it) {
        int d = it * 4 + (t >> 6);
        int r = t & 63;
        int k = klds[r];
        float q  = E[d * KNUM + k];
        float xv = xlds[d * 64 + r];
        float diff = xv - q;
        lsum = fmaf(diff, diff, lsum);
        outbase[d * HWN + r] = q;
    }
    if (t < 64) oidx[n0 + t] = (float)klds[t];

    #pragma unroll
    for (int off = 32; off >= 1; off >>= 1)
        lsum += __shfl_xor(lsum, off);
    if ((t & 63) == 0) redlds[t >> 6] = lsum;
    __syncthreads();
    if (t == 0)
        partial[blockIdx.x] = (redlds[0] + redlds[1]) + (redlds[2] + redlds[3]);
}

__global__ __launch_bounds__(256) void vq_loss_kernel(const float* __restrict__ partial,
                                                      float* __restrict__ out_loss) {
    __shared__ float red[4];
    int t = threadIdx.x;
    float s = 0.f;
    #pragma unroll
    for (int it = 0; it < 4; ++it) s += partial[it * 256 + t];
    #pragma unroll
    for (int off = 32; off >= 1; off >>= 1) s += __shfl_xor(s, off);
    if ((t & 63) == 0) red[t >> 6] = s;
    __syncthreads();
    if (t == 0) {
        float loss = ((red[0] + red[1]) + (red[2] + red[3])) / 4194304.f;
        out_loss[0] = loss;
        out_loss[1] = loss;
    }
}

extern "C" void kernel_launch(void* const* d_in, const int* in_sizes, int n_in,
                              void* d_out, int out_size, void* d_ws, size_t ws_size,
                              hipStream_t stream) {
    const float* x = (const float*)d_in[0];
    const float* E = (const float*)d_in[1];
    float* out      = (float*)d_out;
    float* out_q    = out;
    float* out_loss = out + 4194304;
    float* oidx     = out + 4194306;

    float* esq     = (float*)d_ws;                           // 1024 f32
    float* partial = esq + 1024;                             // 1024 f32
    unsigned short* eh = (unsigned short*)(partial + 1024);  // 65536 us
    unsigned short* el = eh + KNUM * DDIM;                   // 65536 us

    vq_convert_e<<<4, 256, 0, stream>>>(E, esq, eh, el);
    vq_mfma_fused<<<1024, 256, 0, stream>>>(x, E, eh, el, esq, oidx, out_q, partial);
    vq_loss_kernel<<<1, 256, 0, stream>>>(partial, out_loss);
}

// Round 18
// 63.816 us; speedup vs baseline: 1.9728x; 1.0166x over previous
//
#include <hip/hip_runtime.h>

// VQ via MFMA (bf16 hi/lo compensated) + exact-recheck for near-ties. R18.
// x [64,64,32,32] fp32, E [64,1024] fp32. rows n = b*1024+hw, N=65536.
// d_out: [0,4194304) quantized; [4194304] dict_loss; [4194305] commit_loss;
//   [4194306,+65536) indices as float.
// R18 vs R17: (1) esq staged to LDS once -- the per-kt global esq load shared
// vmcnt with the staging global_load_lds ops, so its wait drained the next
// phase's prefetch (the hidden serializer). Now the loop's only vmcnt users
// are staging ops, drained once/phase by the barrier. (2) esq folded into the
// MFMA C-init (C = -esq/2, per-lane splat legal since esq depends only on the
// output column); score = Sxe - esq/2, argmin dist == argmax score -> 4 fma/kt
// removed, flag gap on score scale (EPS/2).

#define DDIM 64
#define KNUM 1024
#define HWN  1024
#define EPSS 0.01f   // EPS(dist)=0.02 -> score scale /2

typedef __attribute__((ext_vector_type(8))) short short8v;
typedef __attribute__((ext_vector_type(4))) float f32x4;

__device__ __forceinline__ unsigned short bf16_rn(float v) {
    unsigned u = __float_as_uint(v);
    return (unsigned short)((u + 0x7FFFu + ((u >> 16) & 1u)) >> 16);
}
__device__ __forceinline__ float bf16f(unsigned short h) {
    return __uint_as_float(((unsigned)h) << 16);
}

// ---- E: esq + bf16 hi/lo split, transposed to [k][d] ----
__global__ __launch_bounds__(256) void vq_convert_e(const float* __restrict__ E,
                                                    float* __restrict__ esq,
                                                    unsigned short* __restrict__ eh,
                                                    unsigned short* __restrict__ el) {
    int k = blockIdx.x * 256 + threadIdx.x;   // grid 4
    float s = 0.f;
    #pragma unroll 8
    for (int d = 0; d < DDIM; ++d) {
        float v = E[d * KNUM + k];
        s = fmaf(v, v, s);
        unsigned short h = bf16_rn(v);
        float lo = v - bf16f(h);              // exact split
        eh[k * DDIM + d] = h;
        el[k * DDIM + d] = bf16_rn(lo);
    }
    esq[k] = s;
}

// ---- fused: MFMA scores + top2 argmax + cleanup + quantized + loss ----
__global__ __launch_bounds__(256, 4) void vq_mfma_fused(const float* __restrict__ x,
                                                        const float* __restrict__ E,
                                                        const unsigned short* __restrict__ eh,
                                                        const unsigned short* __restrict__ el,
                                                        const float* __restrict__ esq,
                                                        float* __restrict__ oidx,
                                                        float* __restrict__ out_q,
                                                        float* __restrict__ partial) {
    // blds[buf]: 4 kt-tiles x (32 rows x 128 B swizzled) = 16 KB per buffer.
    __shared__ unsigned short blds[2][8192];
    __shared__ float esqlds[KNUM];            // 4 KB, staged once
    __shared__ int   klds[64];
    __shared__ float redlds[4];

    const int t = threadIdx.x;
    const int wv = t >> 6, l = t & 63;
    const int m = l & 15, g = l >> 4;
    const int tile = blockIdx.x * 4 + wv;     // grid 1024: 4096 tiles, 1/wave
    const int n0 = blockIdx.x * 64;
    const int b  = n0 >> 10, hw0 = n0 & 1023;

    // ---- stage esq once (4 KB = 256 x 16 B); drained by first barrier ----
    __builtin_amdgcn_global_load_lds(
        (const __attribute__((address_space(1))) void*)(esq + t * 4),
        (__attribute__((address_space(3))) void*)&esqlds[t * 4], 16, 0, 0);

    // ---- staging geometry: 256 threads stage one 4KB kt-tile ----
    const int sr   = t >> 3;                  // row 0..31 in tile
    const int sc   = (t & 7) * 16;            // linear byte col
    const int scsw = sc ^ ((sr & 7) << 4);    // inverse-swizzled source col
    const unsigned short* srcrow0 =
        (sr < 16) ? (eh + (size_t)sr * DDIM + (scsw >> 1))
                  : (el + (size_t)(sr - 16) * DDIM + (scsw >> 1));
    #define STAGEPH(BUF, P)                                                                  \
        _Pragma("unroll")                                                                    \
        for (int q = 0; q < 4; ++q)                                                          \
            __builtin_amdgcn_global_load_lds(                                                \
                (const __attribute__((address_space(1))) void*)(srcrow0 + (size_t)((P) * 4 + q) * 16 * DDIM), \
                (__attribute__((address_space(3))) void*)&blds[BUF][q * 2048 + t * 8],       \
                16, 0, 0);

    // ---- A fragments: load x fp32 (coalesced), split hi/lo in-reg ----
    short8v axh[2], axl[2];
    {
        const int tn0 = tile * 16;
        const int tb = tn0 >> 10, thw = tn0 & 1023;
        const float* xg = x + (size_t)tb * (DDIM * HWN) + thw + m;
        #pragma unroll
        for (int s = 0; s < 2; ++s) {
            #pragma unroll
            for (int i = 0; i < 8; ++i) {
                float v = xg[(s * 32 + g * 8 + i) * HWN];
                unsigned short h = bf16_rn(v);
                axh[s][i] = (short)h;
                axl[s][i] = (short)bf16_rn(v - bf16f(h));
            }
        }
    }

    // swizzled ds_read offsets (shorts) within a kt-tile
    const int off_h0 = (m * 128 + (((g * 16)     ) ^ ((m & 7) << 4))) >> 1;
    const int off_h1 = (m * 128 + (((64 + g * 16)) ^ ((m & 7) << 4))) >> 1;
    const int off_l0 = off_h0 + 1024;
    const int off_l1 = off_h1 + 1024;

    float max1[4], max2[4]; int bk[4];
    #pragma unroll
    for (int j = 0; j < 4; ++j) { max1[j] = -3.4e38f; max2[j] = -3.4e38f; bk[j] = 0; }

    STAGEPH(0, 0);
    __syncthreads();

    for (int p = 0; p < 16; ++p) {
        const int cur = p & 1;
        if (p < 15) STAGEPH(cur ^ 1, p + 1);

        #pragma unroll
        for (int ktl = 0; ktl < 4; ++ktl) {
            const int kt = p * 4 + ktl;
            const unsigned short* bb = &blds[cur][ktl * 2048];
            const short8v bh0 = *reinterpret_cast<const short8v*>(bb + off_h0);
            const short8v bh1 = *reinterpret_cast<const short8v*>(bb + off_h1);
            const short8v bl0 = *reinterpret_cast<const short8v*>(bb + off_l0);
            const short8v bl1 = *reinterpret_cast<const short8v*>(bb + off_l1);
            const float ci = -0.5f * esqlds[kt * 16 + m];   // ds_read, lgkm domain
            const f32x4 cinit = {ci, ci, ci, ci};           // per-col splat (legal)

            f32x4 acc;
            acc = __builtin_amdgcn_mfma_f32_16x16x32_bf16(axh[0], bh0, cinit, 0, 0, 0);
            acc = __builtin_amdgcn_mfma_f32_16x16x32_bf16(axh[1], bh1, acc,  0, 0, 0);
            acc = __builtin_amdgcn_mfma_f32_16x16x32_bf16(axh[0], bl0, acc,  0, 0, 0);
            acc = __builtin_amdgcn_mfma_f32_16x16x32_bf16(axh[1], bl1, acc,  0, 0, 0);
            acc = __builtin_amdgcn_mfma_f32_16x16x32_bf16(axl[0], bh0, acc,  0, 0, 0);
            acc = __builtin_amdgcn_mfma_f32_16x16x32_bf16(axl[1], bh1, acc,  0, 0, 0);

            const int kcur = kt * 16 + m;
            #pragma unroll
            for (int j = 0; j < 4; ++j) {
                float s = acc[j];                       // score = Sxe - esq/2
                max2[j] = fmaxf(fminf(s, max1[j]), max2[j]);   // med3-style
                bool gt = s > max1[j];
                bk[j]   = gt ? kcur : bk[j];
                max1[j] = fmaxf(max1[j], s);
            }
        }
        __syncthreads();
    }
    #undef STAGEPH

    // ---- issue x fp32 staging into dead blds (overlaps with merge below) ----
    float* xlds = reinterpret_cast<float*>(&blds[0][0]);   // 16 KB [d][64 rows]
    {
        const float* xbase = x + (size_t)b * (DDIM * HWN) + hw0;
        #pragma unroll
        for (int it = 0; it < 4; ++it) {
            int dbase = it * 16 + wv * 4;
            int dsub  = l >> 4;
            int off   = (l & 15) * 4;
            const float* gp = xbase + (dbase + dsub) * HWN + off;
            __builtin_amdgcn_global_load_lds(
                (const __attribute__((address_space(1))) void*)gp,
                (__attribute__((address_space(3))) void*)&xlds[dbase * 64 + l * 4],
                16, 0, 0);
        }
    }

    // ---- top-2 merge (max semantics) across the 16 k-class lanes ----
    #pragma unroll
    for (int j = 0; j < 4; ++j) {
        float m1 = max1[j], m2 = max2[j]; int k1 = bk[j];
        #pragma unroll
        for (int off = 8; off >= 1; off >>= 1) {
            float om1 = __shfl_xor(m1, off, 16);
            float om2 = __shfl_xor(m2, off, 16);
            int   ok1 = __shfl_xor(k1, off, 16);
            if (om1 > m1 || (om1 == m1 && ok1 < k1)) {
                m2 = fmaxf(m1, om2); m1 = om1; k1 = ok1;
            } else {
                m2 = fmaxf(m2, (om1 == m1) ? om2 : om1);
            }
        }
        if (m == j) {
            int r = wv * 16 + g * 4 + j;
            klds[r] = (m1 - m2 < EPSS) ? -(k1 + 1) : k1;   // negative = flagged
        }
    }
    __syncthreads();   // xlds staged (vmcnt drained) + klds visible

    // ---- cleanup: exact fp32 recheck for flagged rows (rare) ----
    for (int r = wv; r < 64; r += 4) {
        if (klds[r] >= 0) continue;
        float acc[16];
        #pragma unroll
        for (int kk = 0; kk < 16; ++kk) acc[kk] = 0.f;
        for (int d = 0; d < DDIM; ++d) {
            float xd = xlds[d * 64 + r];                   // broadcast
            #pragma unroll
            for (int kk = 0; kk < 16; ++kk)
                acc[kk] = fmaf(xd, E[d * KNUM + kk * 64 + l], acc[kk]);
        }
        float bm = 3.4e38f; int bkk = KNUM;
        #pragma unroll
        for (int kk = 0; kk < 16; ++kk) {
            int k = kk * 64 + l;
            float dist = fmaf(-2.f, acc[kk], esqlds[k]);
            if (dist < bm) { bm = dist; bkk = k; }         // kk ascending -> first-min
        }
        #pragma unroll
        for (int off = 32; off >= 1; off >>= 1) {
            float ob = __shfl_xor(bm, off);
            int   ok = __shfl_xor(bkk, off);
            if (ob < bm || (ob == bm && ok < bkk)) { bm = ob; bkk = ok; }
        }
        if (l == 0) klds[r] = bkk;
    }
    __syncthreads();

    // ---- gather quantized, write coalesced, loss partial, indices ----
    float lsum = 0.f;
    float* outbase = out_q + (size_t)b * (DDIM * HWN) + hw0;
    #pragma unroll 4
    for (int it = 0; it < 16; ++it) {
        int d = it * 4 + (t >> 6);
        int r = t & 63;
        int k = klds[r];
        float q  = E[d * KNUM + k];
        float xv = xlds[d * 64 + r];
        float diff = xv - q;
        lsum = fmaf(diff, diff, lsum);
        outbase[d * HWN + r] = q;
    }
    if (t < 64) oidx[n0 + t] = (float)klds[t];

    #pragma unroll
    for (int off = 32; off >= 1; off >>= 1)
        lsum += __shfl_xor(lsum, off);
    if ((t & 63) == 0) redlds[t >> 6] = lsum;
    __syncthreads();
    if (t == 0)
        partial[blockIdx.x] = (redlds[0] + redlds[1]) + (redlds[2] + redlds[3]);
}

__global__ __launch_bounds__(256) void vq_loss_kernel(const float* __restrict__ partial,
                                                      float* __restrict__ out_loss) {
    __shared__ float red[4];
    int t = threadIdx.x;
    float s = 0.f;
    #pragma unroll
    for (int it = 0; it < 4; ++it) s += partial[it * 256 + t];
    #pragma unroll
    for (int off = 32; off >= 1; off >>= 1) s += __shfl_xor(s, off);
    if ((t & 63) == 0) red[t >> 6] = s;
    __syncthreads();
    if (t == 0) {
        float loss = ((red[0] + red[1]) + (red[2] + red[3])) / 4194304.f;
        out_loss[0] = loss;
        out_loss[1] = loss;
    }
}

extern "C" void kernel_launch(void* const* d_in, const int* in_sizes, int n_in,
                              void* d_out, int out_size, void* d_ws, size_t ws_size,
                              hipStream_t stream) {
    const float* x = (const float*)d_in[0];
    const float* E = (const float*)d_in[1];
    float* out      = (float*)d_out;
    float* out_q    = out;
    float* out_loss = out + 4194304;
    float* oidx     = out + 4194306;

    float* esq     = (float*)d_ws;                           // 1024 f32
    float* partial = esq + 1024;                             // 1024 f32
    unsigned short* eh = (unsigned short*)(partial + 1024);  // 65536 us
    unsigned short* el = eh + KNUM * DDIM;                   // 65536 us

    vq_convert_e<<<4, 256, 0, stream>>>(E, esq, eh, el);
    vq_mfma_fused<<<1024, 256, 0, stream>>>(x, E, eh, el, esq, oidx, out_q, partial);
    vq_loss_kernel<<<1, 256, 0, stream>>>(partial, out_loss);
}